// Round 4
// baseline (157.906 us; speedup 1.0000x reference)
//
#include <hip/hip_runtime.h>
#include <hip/hip_fp16.h>

#define NB 4
#define CI 64
#define CO 128
#define HH 128
#define WW 128
#define HWSZ (HH*WW)
#define TOTPX (NB*HWSZ)     // 65536
#define NN 9

using short8 = __attribute__((ext_vector_type(8))) short;
using f32x4  = __attribute__((ext_vector_type(4))) float;

__device__ __forceinline__ unsigned f2bf(float f) {      // fp32 -> bf16 bits, RNE
    unsigned u = __float_as_uint(f);
    return (u + 0x7FFFu + ((u >> 16) & 1u)) >> 16;
}

// -------- K0: w_conv[oc][c][3][3] -> wsW bf16 [n][oc][c] --------
__global__ __launch_bounds__(256) void k_prep_w(const float* __restrict__ w,
                                                unsigned short* __restrict__ wsW) {
    int t = blockIdx.x * 256 + threadIdx.x;
    if (t >= CO * 576) return;
    int oc = t / 576, r = t - oc * 576;
    int c = r / 9, n = r - c * 9;
    wsW[(n * CO + oc) * 64 + c] = (unsigned short)f2bf(w[t]);
}

// ---------------- K0b: x NCHW fp32 -> xT NHWC bf16 ----------------
__global__ __launch_bounds__(256) void k_nhwc(const float* __restrict__ x,
                                              unsigned short* __restrict__ xT) {
    __shared__ float tl[64 * 65];
    int bid = blockIdx.x;
    int b = bid >> 8, rem = bid & 255, y = rem >> 1, x0 = (rem & 1) << 6;
    int t = threadIdx.x;
    #pragma unroll
    for (int i = 0; i < 16; i++) {
        int idx = t + i * 256;
        int c = idx >> 6, xl = idx & 63;
        tl[c * 65 + xl] = x[((size_t)(b * CI + c) * HH + y) * WW + x0 + xl];
    }
    __syncthreads();
    #pragma unroll
    for (int i = 0; i < 16; i++) {
        int idx = t + i * 256;
        int xl = idx >> 6, c = idx & 63;
        xT[(size_t)((b * HH + y) * WW + x0 + xl) * 64 + c] =
            (unsigned short)f2bf(tl[c * 65 + xl]);
    }
}

// ------- K1: offset conv (fp32, 4-way ch split, ky-chunked weights) -------
// Emits per-sample gather descriptors: uchar4 corner coords + half4 weights.
__global__ __launch_bounds__(256) void k_offsets(
    const float* __restrict__ x, const float* __restrict__ w_off,
    const float* __restrict__ b_off, uchar4* __restrict__ dC,
    ushort4* __restrict__ dG)
{
    __shared__ float smem[256 * 21];   // phase A: wl[192 rows][18 pad 20]; phase B: partials
    int bid = blockIdx.x;
    int b = bid >> 8, rem = bid & 255, y = rem >> 1, x0 = (rem & 1) << 6;
    int t = threadIdx.x;
    int pxl = t & 63, cq = t >> 6;
    int xg = x0 + pxl;

    float a[18];
    #pragma unroll
    for (int i = 0; i < 18; i++) a[i] = 0.f;

    for (int ky = 0; ky < 3; ky++) {
        __syncthreads();
        // stage weight rows for this ky: [c*3+kx][oc 18 pad 20]
        for (int i = t; i < 192 * 18; i += 256) {
            int oc = i / 192, r = i - oc * 192;
            int c = r / 3, kx = r - c * 3;
            smem[r * 20 + oc] = w_off[oc * 576 + c * 9 + ky * 3 + kx];
        }
        __syncthreads();

        int yy = y + ky - 1;
        bool yok = (unsigned)yy < 128u;
        for (int ci = 0; ci < 16; ci++) {
            int cg = cq * 16 + ci;
            const float* xrow = x + ((size_t)(b * CI + cg) * HH + yy) * WW;
            #pragma unroll
            for (int kx = 0; kx < 3; kx++) {
                int xx = xg + kx - 1;
                float xv = (yok && (unsigned)xx < 128u) ? xrow[xx] : 0.f;
                const f32x4* wr = (const f32x4*)&smem[(cg * 3 + kx) * 20];
                f32x4 w0 = wr[0], w1 = wr[1], w2 = wr[2], w3 = wr[3], w4 = wr[4];
                a[0]  = fmaf(xv, w0[0], a[0]);   a[1]  = fmaf(xv, w0[1], a[1]);
                a[2]  = fmaf(xv, w0[2], a[2]);   a[3]  = fmaf(xv, w0[3], a[3]);
                a[4]  = fmaf(xv, w1[0], a[4]);   a[5]  = fmaf(xv, w1[1], a[5]);
                a[6]  = fmaf(xv, w1[2], a[6]);   a[7]  = fmaf(xv, w1[3], a[7]);
                a[8]  = fmaf(xv, w2[0], a[8]);   a[9]  = fmaf(xv, w2[1], a[9]);
                a[10] = fmaf(xv, w2[2], a[10]);  a[11] = fmaf(xv, w2[3], a[11]);
                a[12] = fmaf(xv, w3[0], a[12]);  a[13] = fmaf(xv, w3[1], a[13]);
                a[14] = fmaf(xv, w3[2], a[14]);  a[15] = fmaf(xv, w3[3], a[15]);
                a[16] = fmaf(xv, w4[0], a[16]);  a[17] = fmaf(xv, w4[1], a[17]);
            }
        }
    }
    __syncthreads();               // weights dead; reuse smem for partials
    #pragma unroll
    for (int i = 0; i < 18; i++) smem[t * 21 + i] = a[i];
    __syncthreads();

    for (int task = t; task < 576; task += 256) {
        int p2 = task & 63, n = task >> 6;
        float ay = b_off[n], ax = b_off[9 + n];
        #pragma unroll
        for (int c2 = 0; c2 < 4; c2++) {
            ay += smem[(c2 * 64 + p2) * 21 + n];
            ax += smem[(c2 * 64 + p2) * 21 + 9 + n];
        }
        float py  = (float)(y + (n / 3)) + ay;
        float pxc = (float)(x0 + p2 + (n % 3)) + ax;
        float fy = floorf(py), fx = floorf(pxc);
        if (py  < 1.f || py  > 128.f) py  = fy;       // pad snap
        if (pxc < 1.f || pxc > 128.f) pxc = fx;
        py  = fminf(fmaxf(py,  0.f), 129.f);
        pxc = fminf(fmaxf(pxc, 0.f), 129.f);

        fy = floorf(py); fx = floorf(pxc);
        int y0 = (int)fy, x0i = (int)fx;              // padded coords [0,129]
        int y1 = min(y0 + 1, 129), x1 = min(x0i + 1, 129);
        float wyl = 1.f + (fy - py);
        float wyr = 1.f - ((float)y1 - py);
        float wxl = 1.f + (fx - pxc);
        float wxr = 1.f - ((float)x1 - pxc);
        float glt = wyl * wxl, grb = wyr * wxr, glb = wyl * wxr, grt = wyr * wxl;
        if ((unsigned)(y0  - 1) >= 128u) { glt = 0.f; glb = 0.f; }
        if ((unsigned)(y1  - 1) >= 128u) { grb = 0.f; grt = 0.f; }
        if ((unsigned)(x0i - 1) >= 128u) { glt = 0.f; grt = 0.f; }
        if ((unsigned)(x1  - 1) >= 128u) { grb = 0.f; glb = 0.f; }

        uchar4 cu;
        cu.x = (unsigned char)min(max(y0  - 1, 0), 127);
        cu.y = (unsigned char)min(max(y1  - 1, 0), 127);
        cu.z = (unsigned char)min(max(x0i - 1, 0), 127);
        cu.w = (unsigned char)min(max(x1  - 1, 0), 127);
        ushort4 gu;
        gu.x = __half_as_ushort(__float2half_rn(glt));
        gu.y = __half_as_ushort(__float2half_rn(grb));
        gu.z = __half_as_ushort(__float2half_rn(glb));
        gu.w = __half_as_ushort(__float2half_rn(grt));
        int pixIdx = (b * HH + y) * WW + x0 + p2;
        dC[n * TOTPX + pixIdx] = cu;
        dG[n * TOTPX + pixIdx] = gu;
    }
}

// ------- K2: register-fragment gather + MFMA. Zero LDS, zero barriers. -------
// Block = 64 px x 128 oc; wave = 16 px x 128 oc. Lane: col=px, koct=k-slice.
__global__ __launch_bounds__(256, 4) void k_main(
    const unsigned short* __restrict__ xT, const unsigned short* __restrict__ wsW,
    const uchar4* __restrict__ dC, const ushort4* __restrict__ dG,
    float* __restrict__ out)
{
    int bid0 = blockIdx.x;                     // XCD-bijective: 1024 = 8 x 128
    int bid  = ((bid0 & 7) << 7) | (bid0 >> 3);
    int b = bid >> 8, rem = bid & 255, y = rem >> 1, x0 = (rem & 1) << 6;

    int t = threadIdx.x, lane = t & 63, wv = t >> 6;
    int col = lane & 15, koct = lane >> 4;
    int pxl = wv * 16 + col;
    int pix = (b * HH + y) * WW + x0 + pxl;
    const unsigned short* xb = xT + (size_t)b * (HWSZ * 64);
    int chb = koct * 8;

    f32x4 acc[8];
    #pragma unroll
    for (int i = 0; i < 8; i++) acc[i] = {0.f, 0.f, 0.f, 0.f};

    uchar4  cu = dC[pix];
    ushort4 gu = dG[pix];

    #pragma unroll 1
    for (int kc = 0; kc < 9; kc++) {
        // prefetch next chunk's descriptor
        uchar4 cu_n; ushort4 gu_n;
        if (kc < 8) { cu_n = dC[(kc + 1) * TOTPX + pix]; gu_n = dG[(kc + 1) * TOTPX + pix]; }

        float g0 = __half2float(__ushort_as_half(gu.x));
        float g1 = __half2float(__ushort_as_half(gu.y));
        float g2 = __half2float(__ushort_as_half(gu.z));
        float g3 = __half2float(__ushort_as_half(gu.w));
        int o00 = (((int)cu.x * WW) + cu.z) << 6;     // *64 ch (bf16 elems)
        int o11 = (((int)cu.y * WW) + cu.w) << 6;
        int o01 = (((int)cu.x * WW) + cu.w) << 6;
        int o10 = (((int)cu.y * WW) + cu.z) << 6;
        const unsigned short* wchunk = wsW + kc * (CO * 64);

        #pragma unroll
        for (int ks = 0; ks < 2; ks++) {
            int cofs = chb + ks * 32;
            short8 r00 = *(const short8*)(xb + o00 + cofs);
            short8 r11 = *(const short8*)(xb + o11 + cofs);
            short8 r01 = *(const short8*)(xb + o01 + cofs);
            short8 r10 = *(const short8*)(xb + o10 + cofs);

            unsigned bw[4];
            #pragma unroll
            for (int m = 0; m < 4; m++) {
                unsigned u00 = ((const unsigned*)&r00)[m];
                unsigned u11 = ((const unsigned*)&r11)[m];
                unsigned u01 = ((const unsigned*)&r01)[m];
                unsigned u10 = ((const unsigned*)&r10)[m];
                float lo = g0 * __uint_as_float(u00 << 16)
                         + g1 * __uint_as_float(u11 << 16)
                         + g2 * __uint_as_float(u01 << 16)
                         + g3 * __uint_as_float(u10 << 16);
                float hi = g0 * __uint_as_float(u00 & 0xFFFF0000u)
                         + g1 * __uint_as_float(u11 & 0xFFFF0000u)
                         + g2 * __uint_as_float(u01 & 0xFFFF0000u)
                         + g3 * __uint_as_float(u10 & 0xFFFF0000u);
                bw[m] = f2bf(lo) | (f2bf(hi) << 16);
            }
            short8 bfrag = *(const short8*)bw;

            short8 af[8];
            #pragma unroll
            for (int i = 0; i < 8; i++)
                af[i] = *(const short8*)(wchunk + (i * 16 + col) * 64 + cofs);
            #pragma unroll
            for (int i = 0; i < 8; i++)
                acc[i] = __builtin_amdgcn_mfma_f32_16x16x32_bf16(
                    af[i], bfrag, acc[i], 0, 0, 0);
        }
        cu = cu_n; gu = gu_n;
    }

    // epilogue: D row -> oc, col -> px (64B segments x4)
    int obase = b * CO * HWSZ + y * WW + x0 + pxl;
    #pragma unroll
    for (int i = 0; i < 8; i++)
        #pragma unroll
        for (int r = 0; r < 4; r++) {
            int oc = i * 16 + koct * 4 + r;
            out[obase + oc * HWSZ] = acc[i][r];
        }
}

extern "C" void kernel_launch(void* const* d_in, const int* in_sizes, int n_in,
                              void* d_out, int out_size, void* d_ws, size_t ws_size,
                              hipStream_t stream) {
    const float* x      = (const float*)d_in[0];
    const float* w_off  = (const float*)d_in[1];
    const float* b_off  = (const float*)d_in[2];
    const float* w_conv = (const float*)d_in[3];
    float* out = (float*)d_out;

    // ws: xT 8MB | dC 2.36MB | dG 4.72MB | wsW 144KB  (total ~15.6MB)
    unsigned short* xT  = (unsigned short*)d_ws;
    uchar4*         dC  = (uchar4*)((char*)d_ws + (size_t)TOTPX * 64 * 2);
    ushort4*        dG  = (ushort4*)((char*)d_ws + (size_t)TOTPX * 64 * 2
                                     + (size_t)NN * TOTPX * 4);
    unsigned short* wsW = (unsigned short*)((char*)d_ws + (size_t)TOTPX * 64 * 2
                                     + (size_t)NN * TOTPX * 4 + (size_t)NN * TOTPX * 8);

    k_prep_w<<<(CO * 576 + 255) / 256, 256, 0, stream>>>(w_conv, wsW);
    k_nhwc<<<1024, 256, 0, stream>>>(x, xT);
    k_offsets<<<1024, 256, 0, stream>>>(x, w_off, b_off, dC, dG);
    k_main<<<1024, 256, 0, stream>>>(xT, wsW, dC, dG, out);
}

// Round 5
// 99.992 us; speedup vs baseline: 1.5792x; 1.5792x over previous
//
#include <hip/hip_runtime.h>
#include <hip/hip_fp16.h>

#define NB 4
#define CI 64
#define CO 128
#define HH 128
#define WW 128
#define HWSZ (HH*WW)
#define TOTPX (NB*HWSZ)     // 65536
#define NN 9

using half8 = __attribute__((ext_vector_type(8))) _Float16;
using f32x4 = __attribute__((ext_vector_type(4))) float;

// ---- K0: prep W (fragment-major f16) + offset-conv weights (tap-major) ----
// waF layout: [(n*16 + i*2 + ks)*512 + lane*8 + e] halfs, lane = koct*16+col,
// so an af fragment load is 64 lanes x 16B fully contiguous (1KB dense).
__global__ __launch_bounds__(256) void k_prep_w(const float* __restrict__ w,
                                                unsigned short* __restrict__ waF,
                                                const float* __restrict__ w_off,
                                                float* __restrict__ wP) {
    int t = blockIdx.x * 256 + threadIdx.x;
    if (t < CO * 576) {
        int oc = t / 576, r = t - oc * 576;
        int c = r / 9, n = r - c * 9;
        int i = oc >> 4, col = oc & 15;
        int ks = c >> 5, koct = (c >> 3) & 3, e = c & 7;
        int lane = koct * 16 + col;
        waF[(n * 16 + i * 2 + ks) * 512 + lane * 8 + e] =
            __half_as_ushort(__float2half_rn(w[t]));
    }
    if (t < 18 * 576) {                       // w_off[oc][cg*9+tap] -> wP[row][oc pad20]
        int oc = t / 576, r = t - oc * 576;
        wP[r * 20 + oc] = w_off[t];
    }
}

// ---------------- K0b: x NCHW fp32 -> xT NHWC fp16 ----------------
__global__ __launch_bounds__(256) void k_nhwc(const float* __restrict__ x,
                                              unsigned short* __restrict__ xT) {
    __shared__ float tl[64 * 65];
    int bid = blockIdx.x;
    int b = bid >> 8, rem = bid & 255, y = rem >> 1, x0 = (rem & 1) << 6;
    int t = threadIdx.x;
    #pragma unroll
    for (int i = 0; i < 16; i++) {
        int idx = t + i * 256;
        int c = idx >> 6, xl = idx & 63;
        tl[c * 65 + xl] = x[((size_t)(b * CI + c) * HH + y) * WW + x0 + xl];
    }
    __syncthreads();
    #pragma unroll
    for (int i = 0; i < 16; i++) {
        int idx = t + i * 256;
        int xl = idx >> 6, c = idx & 63;
        xT[(size_t)((b * HH + y) * WW + x0 + xl) * 64 + c] =
            __half_as_ushort(__float2half_rn(tl[c * 65 + xl]));
    }
}

// ------- K1: offset conv, SGPR weights (no weight LDS), fp32 positions -------
__global__ __launch_bounds__(256, 4) void k_offsets(
    const float* __restrict__ x, const float* __restrict__ wP,
    const float* __restrict__ b_off, uchar4* __restrict__ dC,
    ushort4* __restrict__ dG)
{
    __shared__ float smem[256 * 21];   // reduce phase only (21.5 KB)
    int bid = blockIdx.x;
    int b = bid >> 8, rem = bid & 255, y = rem >> 1, x0 = (rem & 1) << 6;
    int t = threadIdx.x;
    int pxl = t & 63, cq = t >> 6;
    int cqu = __builtin_amdgcn_readfirstlane(cq);   // wave-uniform -> s_loads
    int xg = x0 + pxl;

    float a[18];
    #pragma unroll
    for (int i = 0; i < 18; i++) a[i] = 0.f;

    for (int ci = 0; ci < 16; ci++) {
        int cg = cqu * 16 + ci;
        const float* xpl = x + (size_t)(b * CI + cg) * HWSZ;
        #pragma unroll
        for (int ky = 0; ky < 3; ky++) {
            int yy = y + ky - 1;
            if ((unsigned)yy >= 128u) continue;       // uniform branch
            const float* xr = xpl + yy * WW;
            #pragma unroll
            for (int kx = 0; kx < 3; kx++) {
                int xx = xg + kx - 1;
                float xv = ((unsigned)xx < 128u) ? xr[xx] : 0.f;
                const float* wr = wP + (cg * 9 + ky * 3 + kx) * 20;  // uniform addr
                #pragma unroll
                for (int oc = 0; oc < 18; oc++)
                    a[oc] = fmaf(xv, wr[oc], a[oc]);
            }
        }
    }
    #pragma unroll
    for (int i = 0; i < 18; i++) smem[t * 21 + i] = a[i];
    __syncthreads();

    for (int task = t; task < 576; task += 256) {
        int p2 = task & 63, n = task >> 6;
        float ay = b_off[n], ax = b_off[9 + n];
        #pragma unroll
        for (int c2 = 0; c2 < 4; c2++) {
            ay += smem[(c2 * 64 + p2) * 21 + n];
            ax += smem[(c2 * 64 + p2) * 21 + 9 + n];
        }
        float py  = (float)(y + (n / 3)) + ay;
        float pxc = (float)(x0 + p2 + (n % 3)) + ax;
        float fy = floorf(py), fx = floorf(pxc);
        if (py  < 1.f || py  > 128.f) py  = fy;       // pad snap
        if (pxc < 1.f || pxc > 128.f) pxc = fx;
        py  = fminf(fmaxf(py,  0.f), 129.f);
        pxc = fminf(fmaxf(pxc, 0.f), 129.f);

        fy = floorf(py); fx = floorf(pxc);
        int y0 = (int)fy, x0i = (int)fx;              // padded coords [0,129]
        int y1 = min(y0 + 1, 129), x1 = min(x0i + 1, 129);
        float wyl = 1.f + (fy - py);
        float wyr = 1.f - ((float)y1 - py);
        float wxl = 1.f + (fx - pxc);
        float wxr = 1.f - ((float)x1 - pxc);
        float glt = wyl * wxl, grb = wyr * wxr, glb = wyl * wxr, grt = wyr * wxl;
        if ((unsigned)(y0  - 1) >= 128u) { glt = 0.f; glb = 0.f; }
        if ((unsigned)(y1  - 1) >= 128u) { grb = 0.f; grt = 0.f; }
        if ((unsigned)(x0i - 1) >= 128u) { glt = 0.f; grt = 0.f; }
        if ((unsigned)(x1  - 1) >= 128u) { grb = 0.f; glb = 0.f; }

        uchar4 cu;
        cu.x = (unsigned char)min(max(y0  - 1, 0), 127);
        cu.y = (unsigned char)min(max(y1  - 1, 0), 127);
        cu.z = (unsigned char)min(max(x0i - 1, 0), 127);
        cu.w = (unsigned char)min(max(x1  - 1, 0), 127);
        ushort4 gu;
        gu.x = __half_as_ushort(__float2half_rn(glt));
        gu.y = __half_as_ushort(__float2half_rn(grb));
        gu.z = __half_as_ushort(__float2half_rn(glb));
        gu.w = __half_as_ushort(__float2half_rn(grt));
        int pixIdx = (b * HH + y) * WW + x0 + p2;
        dC[n * TOTPX + pixIdx] = cu;
        dG[n * TOTPX + pixIdx] = gu;
    }
}

// ------- K2: f16 register-fragment gather + MFMA. Zero LDS, zero barriers. ----
// Block = 64 px x 128 oc; wave = 16 px x 128 oc. Lane: col=px, koct=k-slice.
__global__ __launch_bounds__(256, 4) void k_main(
    const unsigned short* __restrict__ xT, const unsigned short* __restrict__ waF,
    const uchar4* __restrict__ dC, const ushort4* __restrict__ dG,
    float* __restrict__ out)
{
    int bid0 = blockIdx.x;                     // XCD-bijective: 1024 = 8 x 128
    int bid  = ((bid0 & 7) << 7) | (bid0 >> 3);
    int b = bid >> 8, rem = bid & 255, y = rem >> 1, x0 = (rem & 1) << 6;

    int t = threadIdx.x, lane = t & 63, wv = t >> 6;
    int col = lane & 15, koct = lane >> 4;
    int pxl = wv * 16 + col;
    int pix = (b * HH + y) * WW + x0 + pxl;
    const unsigned short* xb = xT + (size_t)b * (HWSZ * 64);
    int chb = koct * 8;

    f32x4 acc[8];
    #pragma unroll
    for (int i = 0; i < 8; i++) acc[i] = {0.f, 0.f, 0.f, 0.f};

    uchar4  cu = dC[pix];
    ushort4 gu = dG[pix];

    #pragma unroll 1
    for (int kc = 0; kc < 9; kc++) {
        uchar4 cu_n; ushort4 gu_n;
        if (kc < 8) { cu_n = dC[(kc + 1) * TOTPX + pix]; gu_n = dG[(kc + 1) * TOTPX + pix]; }

        __half2 g0 = __half2half2(__ushort_as_half(gu.x));
        __half2 g1 = __half2half2(__ushort_as_half(gu.y));
        __half2 g2 = __half2half2(__ushort_as_half(gu.z));
        __half2 g3 = __half2half2(__ushort_as_half(gu.w));
        int o00 = (((int)cu.x * WW) + cu.z) << 6;
        int o11 = (((int)cu.y * WW) + cu.w) << 6;
        int o01 = (((int)cu.x * WW) + cu.w) << 6;
        int o10 = (((int)cu.y * WW) + cu.z) << 6;
        const unsigned short* wchunk = waF + kc * 8192;

        #pragma unroll
        for (int ks = 0; ks < 2; ks++) {
            int cofs = chb + ks * 32;
            half8 r00 = *(const half8*)(xb + o00 + cofs);
            half8 r11 = *(const half8*)(xb + o11 + cofs);
            half8 r01 = *(const half8*)(xb + o01 + cofs);
            half8 r10 = *(const half8*)(xb + o10 + cofs);

            __half2 vm[4];
            #pragma unroll
            for (int m = 0; m < 4; m++) {
                __half2 v = __hmul2(((const __half2*)&r00)[m], g0);
                v = __hfma2(((const __half2*)&r11)[m], g1, v);
                v = __hfma2(((const __half2*)&r01)[m], g2, v);
                v = __hfma2(((const __half2*)&r10)[m], g3, v);
                vm[m] = v;
            }
            half8 bfrag = *(const half8*)vm;

            #pragma unroll
            for (int i = 0; i < 8; i++) {
                half8 af = *(const half8*)(wchunk + (i * 2 + ks) * 512 + lane * 8);
                acc[i] = __builtin_amdgcn_mfma_f32_16x16x32_f16(
                    af, bfrag, acc[i], 0, 0, 0);
            }
        }
        cu = cu_n; gu = gu_n;
    }

    // epilogue: D row -> oc, col -> px (64B granules)
    int obase = b * CO * HWSZ + y * WW + x0 + pxl;
    #pragma unroll
    for (int i = 0; i < 8; i++)
        #pragma unroll
        for (int r = 0; r < 4; r++) {
            int oc = i * 16 + koct * 4 + r;
            out[obase + oc * HWSZ] = acc[i][r];
        }
}

extern "C" void kernel_launch(void* const* d_in, const int* in_sizes, int n_in,
                              void* d_out, int out_size, void* d_ws, size_t ws_size,
                              hipStream_t stream) {
    const float* x      = (const float*)d_in[0];
    const float* w_off  = (const float*)d_in[1];
    const float* b_off  = (const float*)d_in[2];
    const float* w_conv = (const float*)d_in[3];
    float* out = (float*)d_out;

    // ws: xT 8MB | dC 2.36MB | dG 4.72MB | waF 144KB | wP 46KB  (~15.3MB)
    char* wsb = (char*)d_ws;
    unsigned short* xT  = (unsigned short*)wsb;
    uchar4*         dC  = (uchar4*)(wsb + (size_t)TOTPX * 64 * 2);
    ushort4*        dG  = (ushort4*)(wsb + (size_t)TOTPX * 64 * 2 + (size_t)NN * TOTPX * 4);
    unsigned short* waF = (unsigned short*)(wsb + (size_t)TOTPX * 64 * 2
                                            + (size_t)NN * TOTPX * 4 + (size_t)NN * TOTPX * 8);
    float*          wP  = (float*)(wsb + (size_t)TOTPX * 64 * 2
                                   + (size_t)NN * TOTPX * 4 + (size_t)NN * TOTPX * 8
                                   + (size_t)CO * 576 * 2);

    k_prep_w<<<(CO * 576 + 255) / 256, 256, 0, stream>>>(w_conv, waF, w_off, wP);
    k_nhwc<<<1024, 256, 0, stream>>>(x, xT);
    k_offsets<<<1024, 256, 0, stream>>>(x, wP, b_off, dC, dG);
    k_main<<<1024, 256, 0, stream>>>(xT, waF, dC, dG, out);
}

// Round 6
// 96.336 us; speedup vs baseline: 1.6391x; 1.0380x over previous
//
#include <hip/hip_runtime.h>
#include <hip/hip_fp16.h>

#define NB 4
#define CI 64
#define CO 128
#define HH 128
#define WW 128
#define HWSZ (HH*WW)
#define TOTPX (NB*HWSZ)     // 65536
#define NN 9

using half8 = __attribute__((ext_vector_type(8))) _Float16;
using f32x4 = __attribute__((ext_vector_type(4))) float;

// ---- K0: prep W (fragment-major f16) + offset-conv weights (tap-major) ----
// waF layout: [(n*16 + i*2 + ks)*512 + lane*8 + e] halfs, lane = koct*16+col,
// so an af fragment load is 64 lanes x 16B fully contiguous (1KB dense).
__global__ __launch_bounds__(256) void k_prep_w(const float* __restrict__ w,
                                                unsigned short* __restrict__ waF,
                                                const float* __restrict__ w_off,
                                                float* __restrict__ wP) {
    int t = blockIdx.x * 256 + threadIdx.x;
    if (t < CO * 576) {
        int oc = t / 576, r = t - oc * 576;
        int c = r / 9, n = r - c * 9;
        int i = oc >> 4, col = oc & 15;
        int ks = c >> 5, koct = (c >> 3) & 3, e = c & 7;
        int lane = koct * 16 + col;
        waF[(n * 16 + i * 2 + ks) * 512 + lane * 8 + e] =
            __half_as_ushort(__float2half_rn(w[t]));
    }
    if (t < 18 * 576) {                       // w_off[oc][cg*9+tap] -> wP[row][oc pad20]
        int oc = t / 576, r = t - oc * 576;
        wP[r * 20 + oc] = w_off[t];
    }
}

// ---------------- K0b: x NCHW fp32 -> xT NHWC fp16 ----------------
__global__ __launch_bounds__(256) void k_nhwc(const float* __restrict__ x,
                                              unsigned short* __restrict__ xT) {
    __shared__ float tl[64 * 65];
    int bid = blockIdx.x;
    int b = bid >> 8, rem = bid & 255, y = rem >> 1, x0 = (rem & 1) << 6;
    int t = threadIdx.x;
    #pragma unroll
    for (int i = 0; i < 16; i++) {
        int idx = t + i * 256;
        int c = idx >> 6, xl = idx & 63;
        tl[c * 65 + xl] = x[((size_t)(b * CI + c) * HH + y) * WW + x0 + xl];
    }
    __syncthreads();
    #pragma unroll
    for (int i = 0; i < 16; i++) {
        int idx = t + i * 256;
        int xl = idx >> 6, c = idx & 63;
        xT[(size_t)((b * HH + y) * WW + x0 + xl) * 64 + c] =
            __half_as_ushort(__float2half_rn(tl[c * 65 + xl]));
    }
}

// ------- K1: offset conv, SGPR weights (no weight LDS), fp32 positions -------
__global__ __launch_bounds__(256, 4) void k_offsets(
    const float* __restrict__ x, const float* __restrict__ wP,
    const float* __restrict__ b_off, uchar4* __restrict__ dC,
    ushort4* __restrict__ dG)
{
    __shared__ float smem[256 * 21];   // reduce phase only (21.5 KB)
    int bid = blockIdx.x;
    int b = bid >> 8, rem = bid & 255, y = rem >> 1, x0 = (rem & 1) << 6;
    int t = threadIdx.x;
    int pxl = t & 63, cq = t >> 6;
    int cqu = __builtin_amdgcn_readfirstlane(cq);   // wave-uniform -> s_loads
    int xg = x0 + pxl;

    float a[18];
    #pragma unroll
    for (int i = 0; i < 18; i++) a[i] = 0.f;

    #pragma unroll 2
    for (int ci = 0; ci < 16; ci++) {
        int cg = cqu * 16 + ci;
        const float* xpl = x + (size_t)(b * CI + cg) * HWSZ;
        #pragma unroll
        for (int ky = 0; ky < 3; ky++) {
            int yy = y + ky - 1;
            if ((unsigned)yy >= 128u) continue;       // uniform branch
            const float* xr = xpl + yy * WW;
            #pragma unroll
            for (int kx = 0; kx < 3; kx++) {
                int xx = xg + kx - 1;
                float xv = ((unsigned)xx < 128u) ? xr[xx] : 0.f;
                const float* wr = wP + (cg * 9 + ky * 3 + kx) * 20;  // uniform addr
                #pragma unroll
                for (int oc = 0; oc < 18; oc++)
                    a[oc] = fmaf(xv, wr[oc], a[oc]);
            }
        }
    }
    #pragma unroll
    for (int i = 0; i < 18; i++) smem[t * 21 + i] = a[i];
    __syncthreads();

    for (int task = t; task < 576; task += 256) {
        int p2 = task & 63, n = task >> 6;
        float ay = b_off[n], ax = b_off[9 + n];
        #pragma unroll
        for (int c2 = 0; c2 < 4; c2++) {
            ay += smem[(c2 * 64 + p2) * 21 + n];
            ax += smem[(c2 * 64 + p2) * 21 + 9 + n];
        }
        float py  = (float)(y + (n / 3)) + ay;
        float pxc = (float)(x0 + p2 + (n % 3)) + ax;
        float fy = floorf(py), fx = floorf(pxc);
        if (py  < 1.f || py  > 128.f) py  = fy;       // pad snap
        if (pxc < 1.f || pxc > 128.f) pxc = fx;
        py  = fminf(fmaxf(py,  0.f), 129.f);
        pxc = fminf(fmaxf(pxc, 0.f), 129.f);

        fy = floorf(py); fx = floorf(pxc);
        int y0 = (int)fy, x0i = (int)fx;              // padded coords [0,129]
        int y1 = min(y0 + 1, 129), x1 = min(x0i + 1, 129);
        float wyl = 1.f + (fy - py);
        float wyr = 1.f - ((float)y1 - py);
        float wxl = 1.f + (fx - pxc);
        float wxr = 1.f - ((float)x1 - pxc);
        float glt = wyl * wxl, grb = wyr * wxr, glb = wyl * wxr, grt = wyr * wxl;
        if ((unsigned)(y0  - 1) >= 128u) { glt = 0.f; glb = 0.f; }
        if ((unsigned)(y1  - 1) >= 128u) { grb = 0.f; grt = 0.f; }
        if ((unsigned)(x0i - 1) >= 128u) { glt = 0.f; grt = 0.f; }
        if ((unsigned)(x1  - 1) >= 128u) { grb = 0.f; glb = 0.f; }

        uchar4 cu;
        cu.x = (unsigned char)min(max(y0  - 1, 0), 127);
        cu.y = (unsigned char)min(max(y1  - 1, 0), 127);
        cu.z = (unsigned char)min(max(x0i - 1, 0), 127);
        cu.w = (unsigned char)min(max(x1  - 1, 0), 127);
        ushort4 gu;
        gu.x = __half_as_ushort(__float2half_rn(glt));
        gu.y = __half_as_ushort(__float2half_rn(grb));
        gu.z = __half_as_ushort(__float2half_rn(glb));
        gu.w = __half_as_ushort(__float2half_rn(grt));
        int pixIdx = (b * HH + y) * WW + x0 + p2;
        dC[n * TOTPX + pixIdx] = cu;
        dG[n * TOTPX + pixIdx] = gu;
    }
}

// ------- K2: f16 gather -> B-frags; W double-buffered in LDS; MFMA -------
// Block = 128 px (one row) x 128 oc, 4 waves. Wave = 32 px x 128 oc.
// Lane: col = px-within-group, koct = k-slice. Grid 512 (XCD-swizzled 8x64).
__global__ __launch_bounds__(256, 2) void k_main(
    const unsigned short* __restrict__ xT, const unsigned short* __restrict__ waF,
    const uchar4* __restrict__ dC, const ushort4* __restrict__ dG,
    float* __restrict__ out)
{
    __shared__ __align__(16) unsigned short Wl[2][8192];   // 2 x 16KB W chunks

    int bid0 = blockIdx.x;                     // 512 = 8 XCD x 64
    int bid  = ((bid0 & 7) << 6) | (bid0 >> 3);
    int b = bid >> 7, y = bid & 127;

    int t = threadIdx.x, lane = t & 63, wv = t >> 6;
    int col = lane & 15, koct = lane >> 4;
    int chb = koct * 8;
    const unsigned short* xb = xT + (size_t)b * (HWSZ * 64);

    int pix0 = (b * HH + y) * WW + wv * 32 + col;   // g=0 pixel
    int pix1 = pix0 + 16;                           // g=1 pixel

    // prologue: stage W chunk 0 into buf 0
    {
        const uint4* gsrc = (const uint4*)waF;
        #pragma unroll
        for (int p = 0; p < 4; p++)
            *((uint4*)&Wl[0][0] + t + p * 256) = gsrc[t + p * 256];
    }
    uchar4  cu0 = dC[pix0], cu1 = dC[pix1];
    ushort4 gu0 = dG[pix0], gu1 = dG[pix1];
    __syncthreads();

    f32x4 acc[2][8];
    #pragma unroll
    for (int g = 0; g < 2; g++)
        #pragma unroll
        for (int i = 0; i < 8; i++) acc[g][i] = {0.f, 0.f, 0.f, 0.f};

    int cur = 0;
    #pragma unroll 1
    for (int kc = 0; kc < 9; kc++) {
        // issue next-chunk stage loads + next descriptors early (hide latency)
        uint4 streg[4];
        uchar4 cu0n, cu1n; ushort4 gu0n, gu1n;
        if (kc < 8) {
            const uint4* gsrc = (const uint4*)(waF + (kc + 1) * 8192);
            #pragma unroll
            for (int p = 0; p < 4; p++) streg[p] = gsrc[t + p * 256];
            cu0n = dC[(kc + 1) * TOTPX + pix0];
            cu1n = dC[(kc + 1) * TOTPX + pix1];
            gu0n = dG[(kc + 1) * TOTPX + pix0];
            gu1n = dG[(kc + 1) * TOTPX + pix1];
        }

        // ---- gather both pixel groups into B fragments ----
        half8 bfrag[2][2];
        #pragma unroll
        for (int g = 0; g < 2; g++) {
            uchar4  cu = g ? cu1 : cu0;
            ushort4 gu = g ? gu1 : gu0;
            __half2 g0 = __half2half2(__ushort_as_half(gu.x));
            __half2 g1 = __half2half2(__ushort_as_half(gu.y));
            __half2 g2 = __half2half2(__ushort_as_half(gu.z));
            __half2 g3 = __half2half2(__ushort_as_half(gu.w));
            int o00 = (((int)cu.x * WW) + cu.z) << 6;
            int o11 = (((int)cu.y * WW) + cu.w) << 6;
            int o01 = (((int)cu.x * WW) + cu.w) << 6;
            int o10 = (((int)cu.y * WW) + cu.z) << 6;
            #pragma unroll
            for (int ks = 0; ks < 2; ks++) {
                int cofs = chb + ks * 32;
                half8 r00 = *(const half8*)(xb + o00 + cofs);
                half8 r11 = *(const half8*)(xb + o11 + cofs);
                half8 r01 = *(const half8*)(xb + o01 + cofs);
                half8 r10 = *(const half8*)(xb + o10 + cofs);
                __half2 vm[4];
                #pragma unroll
                for (int m = 0; m < 4; m++) {
                    __half2 v = __hmul2(((const __half2*)&r00)[m], g0);
                    v = __hfma2(((const __half2*)&r11)[m], g1, v);
                    v = __hfma2(((const __half2*)&r01)[m], g2, v);
                    v = __hfma2(((const __half2*)&r10)[m], g3, v);
                    vm[m] = v;
                }
                bfrag[g][ks] = *(const half8*)vm;
            }
        }

        // ---- MFMA: af from LDS (LGKM pipe), 32 mfma ----
        const unsigned short* wl = &Wl[cur][0];
        #pragma unroll
        for (int ks = 0; ks < 2; ks++) {
            #pragma unroll
            for (int i = 0; i < 8; i++) {
                half8 af = *(const half8*)(wl + (i * 2 + ks) * 512 + lane * 8);
                acc[0][i] = __builtin_amdgcn_mfma_f32_16x16x32_f16(
                    af, bfrag[0][ks], acc[0][i], 0, 0, 0);
                acc[1][i] = __builtin_amdgcn_mfma_f32_16x16x32_f16(
                    af, bfrag[1][ks], acc[1][i], 0, 0, 0);
            }
        }

        // ---- write staged chunk into the other buffer, flip ----
        if (kc < 8) {
            #pragma unroll
            for (int p = 0; p < 4; p++)
                *((uint4*)&Wl[cur ^ 1][0] + t + p * 256) = streg[p];
            cu0 = cu0n; cu1 = cu1n; gu0 = gu0n; gu1 = gu1n;
        }
        __syncthreads();
        cur ^= 1;
    }

    // epilogue: D row -> oc, col -> px
    #pragma unroll
    for (int g = 0; g < 2; g++) {
        int obase = b * CO * HWSZ + y * WW + wv * 32 + g * 16 + col;
        #pragma unroll
        for (int i = 0; i < 8; i++)
            #pragma unroll
            for (int r = 0; r < 4; r++) {
                int oc = i * 16 + koct * 4 + r;
                out[obase + oc * HWSZ] = acc[g][i][r];
            }
    }
}

extern "C" void kernel_launch(void* const* d_in, const int* in_sizes, int n_in,
                              void* d_out, int out_size, void* d_ws, size_t ws_size,
                              hipStream_t stream) {
    const float* x      = (const float*)d_in[0];
    const float* w_off  = (const float*)d_in[1];
    const float* b_off  = (const float*)d_in[2];
    const float* w_conv = (const float*)d_in[3];
    float* out = (float*)d_out;

    // ws: xT 8MB | dC 2.36MB | dG 4.72MB | waF 144KB | wP 46KB  (~15.3MB)
    char* wsb = (char*)d_ws;
    unsigned short* xT  = (unsigned short*)wsb;
    uchar4*         dC  = (uchar4*)(wsb + (size_t)TOTPX * 64 * 2);
    ushort4*        dG  = (ushort4*)(wsb + (size_t)TOTPX * 64 * 2 + (size_t)NN * TOTPX * 4);
    unsigned short* waF = (unsigned short*)(wsb + (size_t)TOTPX * 64 * 2
                                            + (size_t)NN * TOTPX * 4 + (size_t)NN * TOTPX * 8);
    float*          wP  = (float*)(wsb + (size_t)TOTPX * 64 * 2
                                   + (size_t)NN * TOTPX * 4 + (size_t)NN * TOTPX * 8
                                   + (size_t)CO * 576 * 2);

    k_prep_w<<<(CO * 576 + 255) / 256, 256, 0, stream>>>(w_conv, waF, w_off, wP);
    k_nhwc<<<1024, 256, 0, stream>>>(x, xT);
    k_offsets<<<1024, 256, 0, stream>>>(x, wP, b_off, dC, dG);
    k_main<<<512, 256, 0, stream>>>(xT, waF, dC, dG, out);
}

// Round 7
// 89.632 us; speedup vs baseline: 1.7617x; 1.0748x over previous
//
#include <hip/hip_runtime.h>
#include <hip/hip_fp16.h>

#define NB 4
#define CI 64
#define CO 128
#define HH 128
#define WW 128
#define HWSZ (HH*WW)
#define TOTPX (NB*HWSZ)     // 65536
#define NN 9

using half8 = __attribute__((ext_vector_type(8))) _Float16;
using f32x4 = __attribute__((ext_vector_type(4))) float;

__device__ __forceinline__ unsigned f2bf(float f) {
    unsigned u = __float_as_uint(f);
    return (u + 0x7FFFu + ((u >> 16) & 1u)) >> 16;
}

// ---- K0: prep W (fragment-major f16) + offset-conv weights (tap-major) ----
// waF: [(n*16 + i*2 + ks)*512 + lane*8 + e] halfs, lane = koct*16+col.
__global__ __launch_bounds__(256) void k_prep_w(const float* __restrict__ w,
                                                unsigned short* __restrict__ waF,
                                                const float* __restrict__ w_off,
                                                float* __restrict__ wP) {
    int t = blockIdx.x * 256 + threadIdx.x;
    if (t < CO * 576) {
        int oc = t / 576, r = t - oc * 576;
        int c = r / 9, n = r - c * 9;
        int i = oc >> 4, col = oc & 15;
        int ks = c >> 5, koct = (c >> 3) & 3, e = c & 7;
        int lane = koct * 16 + col;
        waF[(n * 16 + i * 2 + ks) * 512 + lane * 8 + e] =
            __half_as_ushort(__float2half_rn(w[t]));
    }
    if (t < 18 * 576) {
        int oc = t / 576, r = t - oc * 576;
        wP[r * 20 + oc] = w_off[t];
    }
}

// ---------------- K0b: x NCHW fp32 -> xT NHWC fp16 ----------------
__global__ __launch_bounds__(256) void k_nhwc(const float* __restrict__ x,
                                              unsigned short* __restrict__ xT) {
    __shared__ float tl[64 * 65];
    int bid = blockIdx.x;
    int b = bid >> 8, rem = bid & 255, y = rem >> 1, x0 = (rem & 1) << 6;
    int t = threadIdx.x;
    #pragma unroll
    for (int i = 0; i < 16; i++) {
        int idx = t + i * 256;
        int c = idx >> 6, xl = idx & 63;
        tl[c * 65 + xl] = x[((size_t)(b * CI + c) * HH + y) * WW + x0 + xl];
    }
    __syncthreads();
    #pragma unroll
    for (int i = 0; i < 16; i++) {
        int idx = t + i * 256;
        int xl = idx >> 6, c = idx & 63;
        xT[(size_t)((b * HH + y) * WW + x0 + xl) * 64 + c] =
            __half_as_ushort(__float2half_rn(tl[c * 65 + xl]));
    }
}

// ------- K1: offset conv, SGPR weights, fp32 positions (numerics frozen) -------
__global__ __launch_bounds__(256, 4) void k_offsets(
    const float* __restrict__ x, const float* __restrict__ wP,
    const float* __restrict__ b_off, uchar4* __restrict__ dC,
    ushort4* __restrict__ dG)
{
    __shared__ float smem[256 * 21];
    int bid = blockIdx.x;
    int b = bid >> 8, rem = bid & 255, y = rem >> 1, x0 = (rem & 1) << 6;
    int t = threadIdx.x;
    int pxl = t & 63, cq = t >> 6;
    int cqu = __builtin_amdgcn_readfirstlane(cq);
    int xg = x0 + pxl;

    float a[18];
    #pragma unroll
    for (int i = 0; i < 18; i++) a[i] = 0.f;

    #pragma unroll 2
    for (int ci = 0; ci < 16; ci++) {
        int cg = cqu * 16 + ci;
        const float* xpl = x + (size_t)(b * CI + cg) * HWSZ;
        #pragma unroll
        for (int ky = 0; ky < 3; ky++) {
            int yy = y + ky - 1;
            if ((unsigned)yy >= 128u) continue;
            const float* xr = xpl + yy * WW;
            #pragma unroll
            for (int kx = 0; kx < 3; kx++) {
                int xx = xg + kx - 1;
                float xv = ((unsigned)xx < 128u) ? xr[xx] : 0.f;
                const float* wr = wP + (cg * 9 + ky * 3 + kx) * 20;
                #pragma unroll
                for (int oc = 0; oc < 18; oc++)
                    a[oc] = fmaf(xv, wr[oc], a[oc]);
            }
        }
    }
    #pragma unroll
    for (int i = 0; i < 18; i++) smem[t * 21 + i] = a[i];
    __syncthreads();

    for (int task = t; task < 576; task += 256) {
        int p2 = task & 63, n = task >> 6;
        float ay = b_off[n], ax = b_off[9 + n];
        #pragma unroll
        for (int c2 = 0; c2 < 4; c2++) {
            ay += smem[(c2 * 64 + p2) * 21 + n];
            ax += smem[(c2 * 64 + p2) * 21 + 9 + n];
        }
        float py  = (float)(y + (n / 3)) + ay;
        float pxc = (float)(x0 + p2 + (n % 3)) + ax;
        float fy = floorf(py), fx = floorf(pxc);
        if (py  < 1.f || py  > 128.f) py  = fy;
        if (pxc < 1.f || pxc > 128.f) pxc = fx;
        py  = fminf(fmaxf(py,  0.f), 129.f);
        pxc = fminf(fmaxf(pxc, 0.f), 129.f);

        fy = floorf(py); fx = floorf(pxc);
        int y0 = (int)fy, x0i = (int)fx;
        int y1 = min(y0 + 1, 129), x1 = min(x0i + 1, 129);
        float wyl = 1.f + (fy - py);
        float wyr = 1.f - ((float)y1 - py);
        float wxl = 1.f + (fx - pxc);
        float wxr = 1.f - ((float)x1 - pxc);
        float glt = wyl * wxl, grb = wyr * wxr, glb = wyl * wxr, grt = wyr * wxl;
        if ((unsigned)(y0  - 1) >= 128u) { glt = 0.f; glb = 0.f; }
        if ((unsigned)(y1  - 1) >= 128u) { grb = 0.f; grt = 0.f; }
        if ((unsigned)(x0i - 1) >= 128u) { glt = 0.f; grt = 0.f; }
        if ((unsigned)(x1  - 1) >= 128u) { grb = 0.f; glb = 0.f; }

        uchar4 cu;
        cu.x = (unsigned char)min(max(y0  - 1, 0), 127);
        cu.y = (unsigned char)min(max(y1  - 1, 0), 127);
        cu.z = (unsigned char)min(max(x0i - 1, 0), 127);
        cu.w = (unsigned char)min(max(x1  - 1, 0), 127);
        ushort4 gu;
        gu.x = __half_as_ushort(__float2half_rn(glt));
        gu.y = __half_as_ushort(__float2half_rn(grb));
        gu.z = __half_as_ushort(__float2half_rn(glb));
        gu.w = __half_as_ushort(__float2half_rn(grt));
        int pixIdx = (b * HH + y) * WW + x0 + p2;
        dC[n * TOTPX + pixIdx] = cu;
        dG[n * TOTPX + pixIdx] = gu;
    }
}

// ------- K2: pipelined gather + W via global_load_lds dbuf + MFMA -------
// Grid 1024 (4 blk/CU). Block = 64 px x 128 oc, 4 waves; wave = 16 px x 128 oc.
__global__ __launch_bounds__(256, 4) void k_main(
    const unsigned short* __restrict__ xT, const unsigned short* __restrict__ waF,
    const uchar4* __restrict__ dC, const ushort4* __restrict__ dG,
    float* __restrict__ out)
{
    __shared__ __align__(16) unsigned short Wl[2][8192];   // 2 x 16KB W chunks

    int bid0 = blockIdx.x;                     // 1024 = 8 XCD x 128
    int bid  = ((bid0 & 7) << 7) | (bid0 >> 3);
    int b = bid >> 8, rem = bid & 255, y = rem >> 1, x0 = (rem & 1) << 6;

    int t = threadIdx.x, lane = t & 63, wv = t >> 6;
    int col = lane & 15, koct = lane >> 4;
    int chb = koct * 8;
    int pxl = wv * 16 + col;
    int pix = (b * HH + y) * WW + x0 + pxl;
    const unsigned short* xb = xT + (size_t)b * (HWSZ * 64);

    // async W chunk stage: 16KB via 4x global_load_lds_dwordx4 per thread-wave
    auto stage = [&](int kc, int buf) {
        #pragma unroll
        for (int p = 0; p < 4; p++) {
            const unsigned short* g = waF + kc * 8192 + wv * 512 + p * 2048 + lane * 8;
            __builtin_amdgcn_global_load_lds(
                (const __attribute__((address_space(1))) unsigned int*)g,
                (__attribute__((address_space(3))) unsigned int*)&Wl[buf][wv * 512 + p * 2048],
                16, 0, 0);
        }
    };

    half8 raw[8];
    auto issue = [&](uchar4 cu) {              // 8 gather loads for one kc
        int o00 = (((int)cu.x * WW) + (int)cu.z) << 6;
        int o11 = (((int)cu.y * WW) + (int)cu.w) << 6;
        int o01 = (((int)cu.x * WW) + (int)cu.w) << 6;
        int o10 = (((int)cu.y * WW) + (int)cu.z) << 6;
        raw[0] = *(const half8*)(xb + o00 + chb);
        raw[1] = *(const half8*)(xb + o11 + chb);
        raw[2] = *(const half8*)(xb + o01 + chb);
        raw[3] = *(const half8*)(xb + o10 + chb);
        raw[4] = *(const half8*)(xb + o00 + chb + 32);
        raw[5] = *(const half8*)(xb + o11 + chb + 32);
        raw[6] = *(const half8*)(xb + o01 + chb + 32);
        raw[7] = *(const half8*)(xb + o10 + chb + 32);
    };

    stage(0, 0);
    uchar4  cuc = dC[pix];          ushort4 guc = dG[pix];
    uchar4  cun = dC[TOTPX + pix];  ushort4 gun = dG[TOTPX + pix];
    issue(cuc);

    f32x4 acc[8];
    #pragma unroll
    for (int i = 0; i < 8; i++) acc[i] = {0.f, 0.f, 0.f, 0.f};
    __syncthreads();                // Wl[0] + raw[kc=0] ready

    int cur = 0;
    #pragma unroll 1
    for (int kc = 0; kc < 9; kc++) {
        if (kc < 8) stage(kc + 1, cur ^ 1);     // async DMA, no regs

        // combine current raws -> B fragments (frees raw regs)
        half8 bfr[2];
        {
            __half2 g0 = __half2half2(__ushort_as_half(guc.x));
            __half2 g1 = __half2half2(__ushort_as_half(guc.y));
            __half2 g2 = __half2half2(__ushort_as_half(guc.z));
            __half2 g3 = __half2half2(__ushort_as_half(guc.w));
            #pragma unroll
            for (int ks = 0; ks < 2; ks++) {
                __half2 vm[4];
                #pragma unroll
                for (int m = 0; m < 4; m++) {
                    __half2 v = __hmul2(((const __half2*)&raw[ks * 4 + 0])[m], g0);
                    v = __hfma2(((const __half2*)&raw[ks * 4 + 1])[m], g1, v);
                    v = __hfma2(((const __half2*)&raw[ks * 4 + 2])[m], g2, v);
                    v = __hfma2(((const __half2*)&raw[ks * 4 + 3])[m], g3, v);
                    vm[m] = v;
                }
                bfr[ks] = *(const half8*)vm;
            }
        }

        // issue next-kc gathers + 2-deep descriptor prefetch (latency hides under MFMA)
        uchar4 cun2 = cun; ushort4 gun2 = gun;
        if (kc < 8) issue(cun);
        if (kc < 7) { cun2 = dC[(kc + 2) * TOTPX + pix]; gun2 = dG[(kc + 2) * TOTPX + pix]; }

        // MFMA: af from LDS (LGKM pipe), 16 mfma
        const unsigned short* wl = &Wl[cur][0];
        #pragma unroll
        for (int ks = 0; ks < 2; ks++)
            #pragma unroll
            for (int i = 0; i < 8; i++) {
                half8 af = *(const half8*)(wl + (i * 2 + ks) * 512 + lane * 8);
                acc[i] = __builtin_amdgcn_mfma_f32_16x16x32_f16(
                    af, bfr[ks], acc[i], 0, 0, 0);
            }

        __syncthreads();            // drains stage(kc+1) + raw(kc+1)
        cur ^= 1;
        cuc = cun; guc = gun; cun = cun2; gun = gun2;
    }

    // epilogue: D row -> oc, col -> px (64B segments)
    int obase = b * CO * HWSZ + y * WW + x0 + pxl;
    #pragma unroll
    for (int i = 0; i < 8; i++)
        #pragma unroll
        for (int r = 0; r < 4; r++) {
            int oc = i * 16 + koct * 4 + r;
            out[obase + oc * HWSZ] = acc[i][r];
        }
}

extern "C" void kernel_launch(void* const* d_in, const int* in_sizes, int n_in,
                              void* d_out, int out_size, void* d_ws, size_t ws_size,
                              hipStream_t stream) {
    const float* x      = (const float*)d_in[0];
    const float* w_off  = (const float*)d_in[1];
    const float* b_off  = (const float*)d_in[2];
    const float* w_conv = (const float*)d_in[3];
    float* out = (float*)d_out;

    // ws: xT 8MB | dC 2.25MB | dG 4.5MB | waF 144KB | wP 46KB
    char* wsb = (char*)d_ws;
    unsigned short* xT  = (unsigned short*)wsb;
    uchar4*         dC  = (uchar4*)(wsb + (size_t)TOTPX * 64 * 2);
    ushort4*        dG  = (ushort4*)(wsb + (size_t)TOTPX * 64 * 2 + (size_t)NN * TOTPX * 4);
    unsigned short* waF = (unsigned short*)(wsb + (size_t)TOTPX * 64 * 2
                                            + (size_t)NN * TOTPX * 4 + (size_t)NN * TOTPX * 8);
    float*          wP  = (float*)(wsb + (size_t)TOTPX * 64 * 2
                                   + (size_t)NN * TOTPX * 4 + (size_t)NN * TOTPX * 8
                                   + (size_t)CO * 576 * 2);

    k_prep_w<<<(CO * 576 + 255) / 256, 256, 0, stream>>>(w_conv, waF, w_off, wP);
    k_nhwc<<<1024, 256, 0, stream>>>(x, xT);
    k_offsets<<<1024, 256, 0, stream>>>(x, wP, b_off, dC, dG);
    k_main<<<1024, 256, 0, stream>>>(xT, waF, dC, dG, out);
}

// Round 8
// 82.732 us; speedup vs baseline: 1.9087x; 1.0834x over previous
//
#include <hip/hip_runtime.h>
#include <hip/hip_fp16.h>

#define NB 4
#define CI 64
#define CO 128
#define HH 128
#define WW 128
#define HWSZ (HH*WW)
#define TOTPX (NB*HWSZ)     // 65536
#define NN 9

using half8 = __attribute__((ext_vector_type(8))) _Float16;
using f32x4 = __attribute__((ext_vector_type(4))) float;

// ---- K0: prep W (fragment-major f16) + offset-conv weights (tap-major) ----
// waF: [(n*16 + i*2 + ks)*512 + lane*8 + e] halfs, lane = koct*16+col.
__global__ __launch_bounds__(256) void k_prep_w(const float* __restrict__ w,
                                                unsigned short* __restrict__ waF,
                                                const float* __restrict__ w_off,
                                                float* __restrict__ wP) {
    int t = blockIdx.x * 256 + threadIdx.x;
    if (t < CO * 576) {
        int oc = t / 576, r = t - oc * 576;
        int c = r / 9, n = r - c * 9;
        int i = oc >> 4, col = oc & 15;
        int ks = c >> 5, koct = (c >> 3) & 3, e = c & 7;
        int lane = koct * 16 + col;
        waF[(n * 16 + i * 2 + ks) * 512 + lane * 8 + e] =
            __half_as_ushort(__float2half_rn(w[t]));
    }
    if (t < 18 * 576) {
        int oc = t / 576, r = t - oc * 576;
        wP[r * 20 + oc] = w_off[t];
    }
}

// -- K1: offset conv (fp32, numerics frozen) + fused NHWC-f16 emit of x --
__global__ __launch_bounds__(256, 4) void k_offsets(
    const float* __restrict__ x, const float* __restrict__ wP,
    const float* __restrict__ b_off, uchar4* __restrict__ dC,
    ushort4* __restrict__ dG, unsigned short* __restrict__ xT)
{
    __shared__ float smem[256 * 21];
    int bid = blockIdx.x;
    int b = bid >> 8, rem = bid & 255, y = rem >> 1, x0 = (rem & 1) << 6;
    int t = threadIdx.x;
    int pxl = t & 63, cq = t >> 6;
    int cqu = __builtin_amdgcn_readfirstlane(cq);
    int xg = x0 + pxl;

    float a[18];
    #pragma unroll
    for (int i = 0; i < 18; i++) a[i] = 0.f;

    #pragma unroll 2
    for (int ci = 0; ci < 16; ci++) {
        int cg = cqu * 16 + ci;
        const float* xpl = x + (size_t)(b * CI + cg) * HWSZ;
        #pragma unroll
        for (int ky = 0; ky < 3; ky++) {
            int yy = y + ky - 1;
            if ((unsigned)yy >= 128u) continue;
            const float* xr = xpl + yy * WW;
            #pragma unroll
            for (int kx = 0; kx < 3; kx++) {
                int xx = xg + kx - 1;
                float xv = ((unsigned)xx < 128u) ? xr[xx] : 0.f;
                const float* wr = wP + (cg * 9 + ky * 3 + kx) * 20;
                #pragma unroll
                for (int oc = 0; oc < 18; oc++)
                    a[oc] = fmaf(xv, wr[oc], a[oc]);
            }
        }
    }

    // fused NHWC f16 emit (replaces k_nhwc): re-read center taps (L1-hot)
    {
        const float* xc = x + ((size_t)(b * CI + cqu * 16) * HH + y) * WW + xg;
        unsigned short c16[16];
        #pragma unroll
        for (int ci = 0; ci < 16; ci++)
            c16[ci] = __half_as_ushort(__float2half_rn(xc[(size_t)ci * HWSZ]));
        size_t pbase = (size_t)((b * HH + y) * WW + xg) * 64 + cqu * 16;
        *(uint4*)(xT + pbase)     = *(const uint4*)&c16[0];
        *(uint4*)(xT + pbase + 8) = *(const uint4*)&c16[8];
    }

    #pragma unroll
    for (int i = 0; i < 18; i++) smem[t * 21 + i] = a[i];
    __syncthreads();

    for (int task = t; task < 576; task += 256) {
        int p2 = task & 63, n = task >> 6;
        float ay = b_off[n], ax = b_off[9 + n];
        #pragma unroll
        for (int c2 = 0; c2 < 4; c2++) {
            ay += smem[(c2 * 64 + p2) * 21 + n];
            ax += smem[(c2 * 64 + p2) * 21 + 9 + n];
        }
        float py  = (float)(y + (n / 3)) + ay;
        float pxc = (float)(x0 + p2 + (n % 3)) + ax;
        float fy = floorf(py), fx = floorf(pxc);
        if (py  < 1.f || py  > 128.f) py  = fy;
        if (pxc < 1.f || pxc > 128.f) pxc = fx;
        py  = fminf(fmaxf(py,  0.f), 129.f);
        pxc = fminf(fmaxf(pxc, 0.f), 129.f);

        fy = floorf(py); fx = floorf(pxc);
        int y0 = (int)fy, x0i = (int)fx;
        int y1 = min(y0 + 1, 129), x1 = min(x0i + 1, 129);
        float wyl = 1.f + (fy - py);
        float wyr = 1.f - ((float)y1 - py);
        float wxl = 1.f + (fx - pxc);
        float wxr = 1.f - ((float)x1 - pxc);
        float glt = wyl * wxl, grb = wyr * wxr, glb = wyl * wxr, grt = wyr * wxl;
        if ((unsigned)(y0  - 1) >= 128u) { glt = 0.f; glb = 0.f; }
        if ((unsigned)(y1  - 1) >= 128u) { grb = 0.f; grt = 0.f; }
        if ((unsigned)(x0i - 1) >= 128u) { glt = 0.f; grt = 0.f; }
        if ((unsigned)(x1  - 1) >= 128u) { grb = 0.f; glb = 0.f; }

        uchar4 cu;
        cu.x = (unsigned char)min(max(y0  - 1, 0), 127);
        cu.y = (unsigned char)min(max(y1  - 1, 0), 127);
        cu.z = (unsigned char)min(max(x0i - 1, 0), 127);
        cu.w = (unsigned char)min(max(x1  - 1, 0), 127);
        ushort4 gu;
        gu.x = __half_as_ushort(__float2half_rn(glt));
        gu.y = __half_as_ushort(__float2half_rn(grb));
        gu.z = __half_as_ushort(__float2half_rn(glb));
        gu.w = __half_as_ushort(__float2half_rn(grt));
        int pixIdx = (b * HH + y) * WW + x0 + p2;
        dC[n * TOTPX + pixIdx] = cu;
        dG[n * TOTPX + pixIdx] = gu;
    }
}

// ------- K2: counted-vmcnt pipeline: gathers + W DMAs fly across barriers ----
// Grid 1024 (4 blk/CU). Block = 64 px x 128 oc, 4 waves; wave = 16 px x 128 oc.
__global__ __launch_bounds__(256, 4) void k_main(
    const unsigned short* __restrict__ xT, const unsigned short* __restrict__ waF,
    const uchar4* __restrict__ dC, const ushort4* __restrict__ dG,
    float* __restrict__ out)
{
    __shared__ __align__(16) unsigned short Wl[2][8192];   // 2 x 16KB W chunks

    int bid0 = blockIdx.x;                     // 1024 = 8 XCD x 128
    int bid  = ((bid0 & 7) << 7) | (bid0 >> 3);
    int b = bid >> 8, rem = bid & 255, y = rem >> 1, x0 = (rem & 1) << 6;

    int t = threadIdx.x, lane = t & 63, wv = t >> 6;
    int col = lane & 15, koct = lane >> 4;
    int chb = koct * 8;
    int pxl = wv * 16 + col;
    int pix = (b * HH + y) * WW + x0 + pxl;
    const unsigned short* xb = xT + (size_t)b * (HWSZ * 64);

    half8 raw[8];
    f32x4 acc[8];
    #pragma unroll
    for (int i = 0; i < 8; i++) acc[i] = {0.f, 0.f, 0.f, 0.f};

    // ---- prologue: stage W(0), 3-deep descriptors, gathers(0) ----
    #pragma unroll
    for (int p = 0; p < 4; p++) {
        const unsigned short* gsrc = waF + wv * 512 + p * 2048 + lane * 8;
        __builtin_amdgcn_global_load_lds(
            (const __attribute__((address_space(1))) unsigned int*)gsrc,
            (__attribute__((address_space(3))) unsigned int*)&Wl[0][wv * 512 + p * 2048],
            16, 0, 0);
    }
    __builtin_amdgcn_sched_barrier(0);
    uchar4 cuA = dC[pix];             ushort4 guA = dG[pix];
    uchar4 cuB = dC[TOTPX + pix];     ushort4 guB = dG[TOTPX + pix];
    uchar4 cuC = dC[2 * TOTPX + pix]; ushort4 guC = dG[2 * TOTPX + pix];
    __builtin_amdgcn_sched_barrier(0);
    {
        int o00 = (((int)cuA.x * WW) + (int)cuA.z) << 6;
        int o11 = (((int)cuA.y * WW) + (int)cuA.w) << 6;
        int o01 = (((int)cuA.x * WW) + (int)cuA.w) << 6;
        int o10 = (((int)cuA.y * WW) + (int)cuA.z) << 6;
        raw[0] = *(const half8*)(xb + o00 + chb);
        raw[1] = *(const half8*)(xb + o11 + chb);
        raw[2] = *(const half8*)(xb + o01 + chb);
        raw[3] = *(const half8*)(xb + o10 + chb);
        raw[4] = *(const half8*)(xb + o00 + chb + 32);
        raw[5] = *(const half8*)(xb + o11 + chb + 32);
        raw[6] = *(const half8*)(xb + o01 + chb + 32);
        raw[7] = *(const half8*)(xb + o10 + chb + 32);
    }
    __builtin_amdgcn_sched_barrier(0);
    asm volatile("s_waitcnt vmcnt(8)" ::: "memory");   // W(0)+descs done; gathers(0) in flight
    __builtin_amdgcn_s_barrier();
    __builtin_amdgcn_sched_barrier(0);

// Per-iteration: [A]stage W(kc+1) [B]desc(kc+3) [C]combine(kc) [D]gathers(kc+1)
// [E]MFMA [F]vmcnt(N)+s_barrier.  N leaves desc+gathers in flight, W-DMA done.
#define ITER(KC)                                                              \
  {                                                                           \
    if ((KC) < 8) {                                                           \
      _Pragma("unroll")                                                       \
      for (int p = 0; p < 4; p++) {                                           \
        const unsigned short* gsrc = waF + ((KC)+1) * 8192 + wv * 512         \
                                     + p * 2048 + lane * 8;                   \
        __builtin_amdgcn_global_load_lds(                                     \
          (const __attribute__((address_space(1))) unsigned int*)gsrc,        \
          (__attribute__((address_space(3))) unsigned int*)                   \
              &Wl[((KC)&1) ^ 1][wv * 512 + p * 2048],                         \
          16, 0, 0);                                                          \
      }                                                                       \
    }                                                                         \
    __builtin_amdgcn_sched_barrier(0);                                        \
    uchar4 cuN; ushort4 guN;                                                  \
    if ((KC) < 6) { cuN = dC[((KC)+3) * TOTPX + pix];                         \
                    guN = dG[((KC)+3) * TOTPX + pix]; }                       \
    __builtin_amdgcn_sched_barrier(0);                                        \
    half8 bfr[2];                                                             \
    { __half2 q0 = __half2half2(__ushort_as_half(guA.x));                     \
      __half2 q1 = __half2half2(__ushort_as_half(guA.y));                     \
      __half2 q2 = __half2half2(__ushort_as_half(guA.z));                     \
      __half2 q3 = __half2half2(__ushort_as_half(guA.w));                     \
      _Pragma("unroll")                                                       \
      for (int ks = 0; ks < 2; ks++) {                                        \
        __half2 vm[4];                                                        \
        _Pragma("unroll")                                                     \
        for (int m = 0; m < 4; m++) {                                         \
          __half2 v = __hmul2(((const __half2*)&raw[ks * 4 + 0])[m], q0);     \
          v = __hfma2(((const __half2*)&raw[ks * 4 + 1])[m], q1, v);          \
          v = __hfma2(((const __half2*)&raw[ks * 4 + 2])[m], q2, v);          \
          v = __hfma2(((const __half2*)&raw[ks * 4 + 3])[m], q3, v);          \
          vm[m] = v; }                                                        \
        bfr[ks] = *(const half8*)vm; } }                                      \
    __builtin_amdgcn_sched_barrier(0);                                        \
    if ((KC) < 8) {                                                           \
      int o00 = (((int)cuB.x * WW) + (int)cuB.z) << 6;                        \
      int o11 = (((int)cuB.y * WW) + (int)cuB.w) << 6;                        \
      int o01 = (((int)cuB.x * WW) + (int)cuB.w) << 6;                        \
      int o10 = (((int)cuB.y * WW) + (int)cuB.z) << 6;                        \
      raw[0] = *(const half8*)(xb + o00 + chb);                               \
      raw[1] = *(const half8*)(xb + o11 + chb);                               \
      raw[2] = *(const half8*)(xb + o01 + chb);                               \
      raw[3] = *(const half8*)(xb + o10 + chb);                               \
      raw[4] = *(const half8*)(xb + o00 + chb + 32);                          \
      raw[5] = *(const half8*)(xb + o11 + chb + 32);                          \
      raw[6] = *(const half8*)(xb + o01 + chb + 32);                          \
      raw[7] = *(const half8*)(xb + o10 + chb + 32);                          \
    }                                                                         \
    __builtin_amdgcn_sched_barrier(0);                                        \
    __builtin_amdgcn_s_setprio(1);                                            \
    { const unsigned short* wl = &Wl[(KC)&1][0];                              \
      _Pragma("unroll")                                                       \
      for (int ks = 0; ks < 2; ks++)                                          \
        _Pragma("unroll")                                                     \
        for (int i = 0; i < 8; i++) {                                         \
          half8 af = *(const half8*)(wl + (i * 2 + ks) * 512 + lane * 8);     \
          acc[i] = __builtin_amdgcn_mfma_f32_16x16x32_f16(af, bfr[ks],        \
                                                          acc[i], 0, 0, 0); } } \
    __builtin_amdgcn_s_setprio(0);                                            \
    if ((KC) < 8) {                                                           \
      if ((KC) <= 5) asm volatile("s_waitcnt vmcnt(10)" ::: "memory");        \
      else           asm volatile("s_waitcnt vmcnt(8)"  ::: "memory");        \
      __builtin_amdgcn_s_barrier();                                           \
      __builtin_amdgcn_sched_barrier(0);                                      \
    }                                                                         \
    cuA = cuB; guA = guB; cuB = cuC; guB = guC;                               \
    if ((KC) < 6) { cuC = cuN; guC = guN; }                                   \
  }

    ITER(0) ITER(1) ITER(2) ITER(3) ITER(4) ITER(5) ITER(6) ITER(7) ITER(8)
#undef ITER

    // epilogue: D row -> oc, col -> px (64B segments)
    int obase = b * CO * HWSZ + y * WW + x0 + pxl;
    #pragma unroll
    for (int i = 0; i < 8; i++)
        #pragma unroll
        for (int r = 0; r < 4; r++) {
            int oc = i * 16 + koct * 4 + r;
            out[obase + oc * HWSZ] = acc[i][r];
        }
}

extern "C" void kernel_launch(void* const* d_in, const int* in_sizes, int n_in,
                              void* d_out, int out_size, void* d_ws, size_t ws_size,
                              hipStream_t stream) {
    const float* x      = (const float*)d_in[0];
    const float* w_off  = (const float*)d_in[1];
    const float* b_off  = (const float*)d_in[2];
    const float* w_conv = (const float*)d_in[3];
    float* out = (float*)d_out;

    // ws: xT 8MB | dC 2.25MB | dG 4.5MB | waF 144KB | wP 46KB
    char* wsb = (char*)d_ws;
    unsigned short* xT  = (unsigned short*)wsb;
    uchar4*         dC  = (uchar4*)(wsb + (size_t)TOTPX * 64 * 2);
    ushort4*        dG  = (ushort4*)(wsb + (size_t)TOTPX * 64 * 2 + (size_t)NN * TOTPX * 4);
    unsigned short* waF = (unsigned short*)(wsb + (size_t)TOTPX * 64 * 2
                                            + (size_t)NN * TOTPX * 4 + (size_t)NN * TOTPX * 8);
    float*          wP  = (float*)(wsb + (size_t)TOTPX * 64 * 2
                                   + (size_t)NN * TOTPX * 4 + (size_t)NN * TOTPX * 8
                                   + (size_t)CO * 576 * 2);

    k_prep_w<<<(CO * 576 + 255) / 256, 256, 0, stream>>>(w_conv, waF, w_off, wP);
    k_offsets<<<1024, 256, 0, stream>>>(x, wP, b_off, dC, dG, xT);
    k_main<<<1024, 256, 0, stream>>>(xT, waF, dC, dG, out);
}